// Round 1
// baseline (1177.292 us; speedup 1.0000x reference)
//
#include <hip/hip_runtime.h>
#include <stdint.h>

#define NSTEPS 40

typedef float  floatx4 __attribute__((ext_vector_type(4)));
typedef __bf16 bf16x8  __attribute__((ext_vector_type(8)));
typedef __bf16 bf16x4  __attribute__((ext_vector_type(4)));

__device__ __forceinline__ __bf16 f2bf(float f){
  union { float f; uint32_t u; } v; v.f = f;
  uint32_t r = v.u + 0x7FFFu + ((v.u >> 16) & 1u);   // RNE
  union { uint16_t s; __bf16 b; } o; o.s = (uint16_t)(r >> 16);
  return o.b;
}
__device__ __forceinline__ float bf2f(__bf16 b){
  union { uint16_t s; __bf16 b; } i; i.b = b;
  union { uint32_t u; float f; } o; o.u = ((uint32_t)i.s) << 16;
  return o.f;
}
__device__ __forceinline__ float fast_tanh(float x){
  // tanh(x) = 1 - 2/(exp(2x)+1); saturates correctly at +/-inf
  float e = __expf(2.0f * x);
  return 1.0f - 2.0f / (e + 1.0f);
}

// ---- prep: bf16-cast + transpose weights into workspace ----
// WsT[n][k] = W_state[k][n]   (256 x 512)
// W1T[n][k] = W_dyn1[k][n]    (256 x 256, rows k<256 only; t-row handled as bias)
// W2T[n2][k]= W_dyn2[k][n2]   (256 x 256)
__global__ void prep_kernel(const float* __restrict__ Ws,
                            const float* __restrict__ W1,
                            const float* __restrict__ W2,
                            __bf16* __restrict__ WsT,
                            __bf16* __restrict__ W1T,
                            __bf16* __restrict__ W2T){
  int tid = blockIdx.x * blockDim.x + threadIdx.x;
  int stride = gridDim.x * blockDim.x;
  for (int i = tid; i < 512*256; i += stride){
    int k = i >> 8, n = i & 255;
    WsT[n*512 + k] = f2bf(Ws[i]);
  }
  for (int i = tid; i < 256*256; i += stride){
    int k = i >> 8, n = i & 255;
    W1T[n*256 + k] = f2bf(W1[i]);
    W2T[n*256 + k] = f2bf(W2[i]);
  }
}

// Fused ODE kernel. Block = 64 batch rows, 256 threads (4 waves).
// Transposed compute: state S = h^T [hid=256][batch=64] held in C/D-layout regs;
// wave w owns hid rows [64w, 64w+64). LDS: W1^T (128KB, swizzled) + state buf
// SB [batch][hid] bf16 (32KB, swizzled) = exactly 160 KiB.
// Swizzle: 16B chunk c of row r lives at chunk (c ^ (r&31)).
__global__ __launch_bounds__(256, 1)
void ode_kernel(const float* __restrict__ x,
                const float* __restrict__ b_state,
                const float* __restrict__ W1full,   // 257x256 fp32 (row 256 = t row)
                const float* __restrict__ b1,
                const float* __restrict__ b2,
                const float* __restrict__ Wout,     // 256x18 fp32
                const float* __restrict__ bout,     // 18 fp32
                const __bf16* __restrict__ WsT,     // [256][512]
                const __bf16* __restrict__ W1Tg,    // [256][256]
                const __bf16* __restrict__ W2Tg,    // [256][256]
                float* __restrict__ out)
{
  __shared__ __align__(16) __bf16 lds_w1[256*256];  // 128 KB
  __shared__ __align__(16) __bf16 lds_sb[64*256];   //  32 KB

  const int tid  = threadIdx.x;
  const int wave = tid >> 6;
  const int lane = tid & 63;
  const int c16  = lane & 15;
  const int q    = lane >> 4;      // 0..3
  const int nh0  = wave * 64;      // this wave's hid-row base
  const int m0   = blockIdx.x * 64;

  // ---- stage W1^T into LDS (swizzled), once ----
  #pragma unroll 4
  for (int it = 0; it < 32; ++it){
    int i = it * 256 + tid;        // 8192 16B chunks
    int row = i >> 5, c = i & 31;
    bf16x8 v = *(const bf16x8*)&W1Tg[row*256 + c*8];
    *(bf16x8*)&lds_w1[row*256 + ((c ^ (row & 31)) << 3)] = v;
  }

  // ---- per-lane bias vectors (row n = nh0 + mt*16 + 4q + r) ----
  floatx4 b1v[4], wtv[4], b2v[4];
  floatx4 g[4][4], hv[4][4];       // [hid-tile mt][batch-tile nt]
  #pragma unroll
  for (int mt = 0; mt < 4; ++mt)
    #pragma unroll
    for (int r = 0; r < 4; ++r){
      int n = nh0 + mt*16 + 4*q + r;
      b1v[mt][r] = b1[n];
      wtv[mt][r] = W1full[256*256 + n];  // time row of W_dyn1
      b2v[mt][r] = b2[n];
    }

  // ---- phase 0: h0^T = tanh(Ws^T @ x^T + b_state) ----
  {
    floatx4 bsv[4];
    #pragma unroll
    for (int mt = 0; mt < 4; ++mt)
      #pragma unroll
      for (int r = 0; r < 4; ++r)
        bsv[mt][r] = b_state[nh0 + mt*16 + 4*q + r];
    #pragma unroll
    for (int mt = 0; mt < 4; ++mt)
      #pragma unroll
      for (int nt = 0; nt < 4; ++nt)
        g[mt][nt] = bsv[mt];
    #pragma unroll
    for (int kt = 0; kt < 16; ++kt){
      bf16x8 a[4], b[4];
      #pragma unroll
      for (int mt = 0; mt < 4; ++mt)
        a[mt] = *(const bf16x8*)&WsT[(nh0 + mt*16 + c16)*512 + kt*32 + q*8];
      #pragma unroll
      for (int nt = 0; nt < 4; ++nt){
        const float* px = &x[(size_t)(m0 + nt*16 + c16)*512 + kt*32 + q*8];
        floatx4 f0 = *(const floatx4*)px;
        floatx4 f1 = *(const floatx4*)(px + 4);
        bf16x8 bb;
        #pragma unroll
        for (int j = 0; j < 4; ++j){ bb[j] = f2bf(f0[j]); bb[4+j] = f2bf(f1[j]); }
        b[nt] = bb;
      }
      #pragma unroll
      for (int mt = 0; mt < 4; ++mt)
        #pragma unroll
        for (int nt = 0; nt < 4; ++nt)
          g[mt][nt] = __builtin_amdgcn_mfma_f32_16x16x32_bf16(a[mt], b[nt], g[mt][nt], 0, 0, 0);
    }
    #pragma unroll
    for (int mt = 0; mt < 4; ++mt)
      #pragma unroll
      for (int nt = 0; nt < 4; ++nt)
        #pragma unroll
        for (int r = 0; r < 4; ++r)
          hv[mt][nt][r] = fast_tanh(g[mt][nt][r]);
  }

  const float dt  = 1.0f / NSTEPS;
  const float dt6 = dt / 6.0f;
  const floatx4 vzero = {0.f, 0.f, 0.f, 0.f};

  for (int s = 0; s < NSTEPS; ++s){
    float tbase = dt * (float)s;
    floatx4 sm[4][4];
    #pragma unroll
    for (int mt = 0; mt < 4; ++mt)
      #pragma unroll
      for (int nt = 0; nt < 4; ++nt)
        sm[mt][nt] = vzero;

    #pragma unroll 1
    for (int e = 0; e < 4; ++e){
      float half_or_full = (e == 3) ? dt : 0.5f * dt;
      float cin = (e == 0) ? 0.0f : half_or_full;   // h_eval = h + cin*k_prev
      float te  = tbase + ((e == 0) ? 0.0f : half_or_full);
      float we  = (e == 1 || e == 2) ? 2.0f : 1.0f;

      __syncthreads();  // prev GEMM2 reads of SB done before overwrite
      // write h_eval (bf16) to SB[batch][hid]; g holds k_{e-1} (cin=0 at e=0)
      #pragma unroll
      for (int mt = 0; mt < 4; ++mt){
        int n0 = nh0 + mt*16 + 4*q;
        #pragma unroll
        for (int nt = 0; nt < 4; ++nt){
          int m = nt*16 + c16;
          bf16x4 wv;
          #pragma unroll
          for (int r = 0; r < 4; ++r)
            wv[r] = f2bf(hv[mt][nt][r] + cin * g[mt][nt][r]);
          *(bf16x4*)&lds_sb[m*256 + (((n0 >> 3) ^ (m & 31)) << 3) + (n0 & 7)] = wv;
        }
      }
      __syncthreads();

      // GEMM1: z^T = W1^T @ h_eval^T  (+ b1 + t*W1_trow), A from LDS-resident W1T
      #pragma unroll
      for (int mt = 0; mt < 4; ++mt){
        floatx4 bias = b1v[mt] + te * wtv[mt];
        #pragma unroll
        for (int nt = 0; nt < 4; ++nt) g[mt][nt] = bias;
      }
      #pragma unroll
      for (int kt = 0; kt < 8; ++kt){
        bf16x8 a[4], b[4];
        #pragma unroll
        for (int mt = 0; mt < 4; ++mt){
          int n = nh0 + mt*16 + c16;
          a[mt] = *(const bf16x8*)&lds_w1[n*256 + (((kt*4 + q) ^ (n & 31)) << 3)];
        }
        #pragma unroll
        for (int nt = 0; nt < 4; ++nt){
          int m = nt*16 + c16;
          b[nt] = *(const bf16x8*)&lds_sb[m*256 + (((kt*4 + q) ^ (m & 31)) << 3)];
        }
        #pragma unroll
        for (int mt = 0; mt < 4; ++mt)
          #pragma unroll
          for (int nt = 0; nt < 4; ++nt)
            g[mt][nt] = __builtin_amdgcn_mfma_f32_16x16x32_bf16(a[mt], b[nt], g[mt][nt], 0, 0, 0);
      }
      __syncthreads();

      // z = tanh(.) -> SB
      #pragma unroll
      for (int mt = 0; mt < 4; ++mt){
        int n0 = nh0 + mt*16 + 4*q;
        #pragma unroll
        for (int nt = 0; nt < 4; ++nt){
          int m = nt*16 + c16;
          bf16x4 wv;
          #pragma unroll
          for (int r = 0; r < 4; ++r)
            wv[r] = f2bf(fast_tanh(g[mt][nt][r]));
          *(bf16x4*)&lds_sb[m*256 + (((n0 >> 3) ^ (m & 31)) << 3) + (n0 & 7)] = wv;
        }
      }
      __syncthreads();

      // GEMM2: k^T = W2^T @ z^T (+b2), A streamed from L2-resident W2T
      #pragma unroll
      for (int mt = 0; mt < 4; ++mt)
        #pragma unroll
        for (int nt = 0; nt < 4; ++nt)
          g[mt][nt] = b2v[mt];
      bf16x8 a_c[4], a_n[4];
      #pragma unroll
      for (int mt = 0; mt < 4; ++mt)
        a_c[mt] = *(const bf16x8*)&W2Tg[(nh0 + mt*16 + c16)*256 + q*8];
      #pragma unroll
      for (int kt = 0; kt < 8; ++kt){
        if (kt < 7){
          #pragma unroll
          for (int mt = 0; mt < 4; ++mt)
            a_n[mt] = *(const bf16x8*)&W2Tg[(nh0 + mt*16 + c16)*256 + (kt+1)*32 + q*8];
        }
        bf16x8 b[4];
        #pragma unroll
        for (int nt = 0; nt < 4; ++nt){
          int m = nt*16 + c16;
          b[nt] = *(const bf16x8*)&lds_sb[m*256 + (((kt*4 + q) ^ (m & 31)) << 3)];
        }
        #pragma unroll
        for (int mt = 0; mt < 4; ++mt)
          #pragma unroll
          for (int nt = 0; nt < 4; ++nt)
            g[mt][nt] = __builtin_amdgcn_mfma_f32_16x16x32_bf16(a_c[mt], b[nt], g[mt][nt], 0, 0, 0);
        if (kt < 7){
          #pragma unroll
          for (int mt = 0; mt < 4; ++mt) a_c[mt] = a_n[mt];
        }
      }

      // RK4 sum
      #pragma unroll
      for (int mt = 0; mt < 4; ++mt)
        #pragma unroll
        for (int nt = 0; nt < 4; ++nt)
          sm[mt][nt] += we * g[mt][nt];
    } // evals

    #pragma unroll
    for (int mt = 0; mt < 4; ++mt)
      #pragma unroll
      for (int nt = 0; nt < 4; ++nt)
        hv[mt][nt] += dt6 * sm[mt][nt];
  } // steps

  // ---- epilogue: hT -> SB, then out = hT @ Wout + bout (VALU, tiny) ----
  __syncthreads();
  #pragma unroll
  for (int mt = 0; mt < 4; ++mt){
    int n0 = nh0 + mt*16 + 4*q;
    #pragma unroll
    for (int nt = 0; nt < 4; ++nt){
      int m = nt*16 + c16;
      bf16x4 wv;
      #pragma unroll
      for (int r = 0; r < 4; ++r) wv[r] = f2bf(hv[mt][nt][r]);
      *(bf16x4*)&lds_sb[m*256 + (((n0 >> 3) ^ (m & 31)) << 3) + (n0 & 7)] = wv;
    }
  }
  __syncthreads();
  {
    const int ml = tid & 63;
    const int og = tid >> 6;           // wave-uniform output group
    const int obase = og * 5;
    const int ocnt = (og == 3) ? 3 : 5;  // 5+5+5+3 = 18
    float acc[5] = {0.f, 0.f, 0.f, 0.f, 0.f};
    for (int c = 0; c < 32; ++c){
      bf16x8 h8 = *(const bf16x8*)&lds_sb[ml*256 + ((c ^ (ml & 31)) << 3)];
      #pragma unroll
      for (int j = 0; j < 8; ++j){
        float hval = bf2f(h8[j]);
        int kk = c*8 + j;
        #pragma unroll
        for (int oo = 0; oo < 5; ++oo)
          if (oo < ocnt) acc[oo] += hval * Wout[kk*18 + obase + oo];
      }
    }
    #pragma unroll
    for (int oo = 0; oo < 5; ++oo)
      if (oo < ocnt) out[(size_t)(m0 + ml)*18 + obase + oo] = acc[oo] + bout[obase + oo];
  }
}

extern "C" void kernel_launch(void* const* d_in, const int* in_sizes, int n_in,
                              void* d_out, int out_size, void* d_ws, size_t ws_size,
                              hipStream_t stream){
  const float* x   = (const float*)d_in[0];
  const float* Ws  = (const float*)d_in[1];
  const float* bs  = (const float*)d_in[2];
  const float* W1  = (const float*)d_in[3];
  const float* b1  = (const float*)d_in[4];
  const float* W2  = (const float*)d_in[5];
  const float* b2  = (const float*)d_in[6];
  const float* Wo  = (const float*)d_in[7];
  const float* bo  = (const float*)d_in[8];
  float* out = (float*)d_out;

  __bf16* WsT = (__bf16*)d_ws;          // 256x512 bf16 = 256 KB
  __bf16* W1T = WsT + 512*256;          // 256x256 bf16 = 128 KB
  __bf16* W2T = W1T + 256*256;          // 256x256 bf16 = 128 KB

  prep_kernel<<<128, 256, 0, stream>>>(Ws, W1, W2, WsT, W1T, W2T);
  ode_kernel<<<256, 256, 0, stream>>>(x, bs, W1, b1, b2, Wo, bo, WsT, W1T, W2T, out);
}

// Round 2
// 1139.294 us; speedup vs baseline: 1.0334x; 1.0334x over previous
//
#include <hip/hip_runtime.h>
#include <stdint.h>

#define NSTEPS 40

typedef float    floatx4  __attribute__((ext_vector_type(4)));
typedef __bf16   bf16x8   __attribute__((ext_vector_type(8)));
typedef uint32_t uint32x2 __attribute__((ext_vector_type(2)));

__device__ __forceinline__ __bf16 f2bf(float f){
  union { float f; uint32_t u; } v; v.f = f;
  uint32_t r = v.u + 0x7FFFu + ((v.u >> 16) & 1u);   // RNE (cold path only)
  union { uint16_t s; __bf16 b; } o; o.s = (uint16_t)(r >> 16);
  return o.b;
}
__device__ __forceinline__ float bf2f(__bf16 b){
  union { uint16_t s; __bf16 b; } i; i.b = b;
  union { uint32_t u; float f; } o; o.u = ((uint32_t)i.s) << 16;
  return o.f;
}
// HW packed f32x2 -> bf16x2 (RNE), 1 instruction
__device__ __forceinline__ uint32_t cvt_pk_bf16(float lo, float hi){
  uint32_t d;
  asm("v_cvt_pk_bf16_f32 %0, %1, %2" : "=v"(d) : "v"(lo), "v"(hi));
  return d;
}
__device__ __forceinline__ float fast_tanh(float x){
  // tanh(x) = 1 - 2/(exp(2x)+1); v_exp + v_rcp, no precise-div sequence
  float e = __expf(2.0f * x);
  return __builtin_fmaf(-2.0f, __builtin_amdgcn_rcpf(e + 1.0f), 1.0f);
}

// ---- prep: bf16-cast + transpose weights into workspace ----
__global__ void prep_kernel(const float* __restrict__ Ws,
                            const float* __restrict__ W1,
                            const float* __restrict__ W2,
                            __bf16* __restrict__ WsT,
                            __bf16* __restrict__ W1T,
                            __bf16* __restrict__ W2T){
  int tid = blockIdx.x * blockDim.x + threadIdx.x;
  int stride = gridDim.x * blockDim.x;
  for (int i = tid; i < 512*256; i += stride){
    int k = i >> 8, n = i & 255;
    WsT[n*512 + k] = f2bf(Ws[i]);
  }
  for (int i = tid; i < 256*256; i += stride){
    int k = i >> 8, n = i & 255;
    W1T[n*256 + k] = f2bf(W1[i]);
    W2T[n*256 + k] = f2bf(W2[i]);
  }
}

// Fused ODE kernel. Block = 64 batch rows, 512 threads (8 waves, 2/SIMD).
// Wave w owns hid rows [32w, 32w+32)  (mt in {0,1}, 16 rows each).
// Transposed compute: z^T = W1^T h^T, k^T = W2^T z^T; state in C/D-layout regs.
// LDS: W1^T (128KB, swizzled) + state buf SB [batch][hid] bf16 (32KB) = 160 KiB.
// Swizzle: 16B chunk c of row r lives at chunk (c ^ (r&31)).
__global__ __launch_bounds__(512, 2)
void ode_kernel(const float* __restrict__ x,
                const float* __restrict__ b_state,
                const float* __restrict__ W1full,   // 257x256 fp32 (row 256 = t row)
                const float* __restrict__ b1,
                const float* __restrict__ b2,
                const float* __restrict__ Wout,     // 256x18 fp32
                const float* __restrict__ bout,
                const __bf16* __restrict__ WsT,     // [256][512]
                const __bf16* __restrict__ W1Tg,    // [256][256]
                const __bf16* __restrict__ W2Tg,    // [256][256]
                float* __restrict__ out)
{
  __shared__ __align__(16) __bf16 lds_w1[256*256];  // 128 KB
  __shared__ __align__(16) __bf16 lds_sb[64*256];   //  32 KB

  const int tid  = threadIdx.x;
  const int wave = tid >> 6;       // 0..7
  const int lane = tid & 63;
  const int c16  = lane & 15;
  const int q    = lane >> 4;      // 0..3
  const int nh0  = wave * 32;      // this wave's hid-row base
  const int m0   = blockIdx.x * 64;

  // ---- stage W1^T into LDS (swizzled), once ----
  #pragma unroll 4
  for (int it = 0; it < 16; ++it){
    int i = it * 512 + tid;        // 8192 16B chunks
    int row = i >> 5, c = i & 31;
    bf16x8 v = *(const bf16x8*)&W1Tg[row*256 + c*8];
    *(bf16x8*)&lds_w1[row*256 + ((c ^ (row & 31)) << 3)] = v;
  }

  // ---- per-lane constants ----
  floatx4 b1v[2], wtv[2], b2v[2];
  floatx4 g[2][4], hv[2][4];       // [hid-tile mt][batch-tile nt]
  int arow[2], abase[2], akey[2];  // A-operand rows (hid), LDS addressing
  int bbase[4], bkey[4];           // B-operand rows (batch)
  int woff[2][4];                  // SB write offsets (constant across evals)
  #pragma unroll
  for (int mt = 0; mt < 2; ++mt){
    int n = nh0 + mt*16 + c16;
    arow[mt] = n; abase[mt] = n*256; akey[mt] = n & 31;
    #pragma unroll
    for (int r = 0; r < 4; ++r){
      int nn = nh0 + mt*16 + 4*q + r;
      b1v[mt][r] = b1[nn];
      wtv[mt][r] = W1full[256*256 + nn];
      b2v[mt][r] = b2[nn];
    }
  }
  #pragma unroll
  for (int nt = 0; nt < 4; ++nt){
    int m = nt*16 + c16;
    bbase[nt] = m*256; bkey[nt] = m & 31;
  }
  #pragma unroll
  for (int mt = 0; mt < 2; ++mt){
    int n0 = nh0 + mt*16 + 4*q;
    #pragma unroll
    for (int nt = 0; nt < 4; ++nt)
      woff[mt][nt] = bbase[nt] + (((n0 >> 3) ^ bkey[nt]) << 3) + (n0 & 7);
  }

  // ---- phase 0: h0^T = tanh(Ws^T @ x^T + b_state) ----
  {
    #pragma unroll
    for (int mt = 0; mt < 2; ++mt){
      floatx4 bsv;
      #pragma unroll
      for (int r = 0; r < 4; ++r) bsv[r] = b_state[nh0 + mt*16 + 4*q + r];
      #pragma unroll
      for (int nt = 0; nt < 4; ++nt) g[mt][nt] = bsv;
    }
    #pragma unroll
    for (int kt = 0; kt < 16; ++kt){
      bf16x8 a[2], b[4];
      #pragma unroll
      for (int mt = 0; mt < 2; ++mt)
        a[mt] = *(const bf16x8*)&WsT[arow[mt]*512 + kt*32 + q*8];
      #pragma unroll
      for (int nt = 0; nt < 4; ++nt){
        const float* px = &x[(size_t)(m0 + nt*16 + c16)*512 + kt*32 + q*8];
        floatx4 f0 = *(const floatx4*)px;
        floatx4 f1 = *(const floatx4*)(px + 4);
        uint32x2 lo = { cvt_pk_bf16(f0[0], f0[1]), cvt_pk_bf16(f0[2], f0[3]) };
        uint32x2 hi = { cvt_pk_bf16(f1[0], f1[1]), cvt_pk_bf16(f1[2], f1[3]) };
        union { uint32_t u[4]; bf16x8 v; } pk;
        pk.u[0]=lo[0]; pk.u[1]=lo[1]; pk.u[2]=hi[0]; pk.u[3]=hi[1];
        b[nt] = pk.v;
      }
      #pragma unroll
      for (int mt = 0; mt < 2; ++mt)
        #pragma unroll
        for (int nt = 0; nt < 4; ++nt)
          g[mt][nt] = __builtin_amdgcn_mfma_f32_16x16x32_bf16(a[mt], b[nt], g[mt][nt], 0, 0, 0);
    }
    #pragma unroll
    for (int mt = 0; mt < 2; ++mt)
      #pragma unroll
      for (int nt = 0; nt < 4; ++nt)
        #pragma unroll
        for (int r = 0; r < 4; ++r)
          hv[mt][nt][r] = fast_tanh(g[mt][nt][r]);
  }

  const float dt  = 1.0f / NSTEPS;
  const float dt6 = dt / 6.0f;
  const floatx4 vzero = {0.f, 0.f, 0.f, 0.f};

  for (int s = 0; s < NSTEPS; ++s){
    float tbase = dt * (float)s;
    floatx4 sm[2][4];
    #pragma unroll
    for (int mt = 0; mt < 2; ++mt)
      #pragma unroll
      for (int nt = 0; nt < 4; ++nt)
        sm[mt][nt] = vzero;

    #pragma unroll 1
    for (int e = 0; e < 4; ++e){
      float half_or_full = (e == 3) ? dt : 0.5f * dt;
      float cin = (e == 0) ? 0.0f : half_or_full;   // h_eval = h + cin*k_prev
      float te  = tbase + ((e == 0) ? 0.0f : half_or_full);
      float we  = (e == 1 || e == 2) ? 2.0f : 1.0f;

      __syncthreads();  // prev GEMM2 reads of SB done before overwrite
      #pragma unroll
      for (int mt = 0; mt < 2; ++mt)
        #pragma unroll
        for (int nt = 0; nt < 4; ++nt){
          float v0 = __builtin_fmaf(cin, g[mt][nt][0], hv[mt][nt][0]);
          float v1 = __builtin_fmaf(cin, g[mt][nt][1], hv[mt][nt][1]);
          float v2 = __builtin_fmaf(cin, g[mt][nt][2], hv[mt][nt][2]);
          float v3 = __builtin_fmaf(cin, g[mt][nt][3], hv[mt][nt][3]);
          uint32x2 wv = { cvt_pk_bf16(v0, v1), cvt_pk_bf16(v2, v3) };
          *(uint32x2*)&lds_sb[woff[mt][nt]] = wv;
        }
      __syncthreads();

      // GEMM1: z^T = W1^T @ h_eval^T (+ b1 + t*w_t), A from LDS-resident W1T
      #pragma unroll
      for (int mt = 0; mt < 2; ++mt){
        floatx4 bias;
        #pragma unroll
        for (int r = 0; r < 4; ++r) bias[r] = __builtin_fmaf(te, wtv[mt][r], b1v[mt][r]);
        #pragma unroll
        for (int nt = 0; nt < 4; ++nt) g[mt][nt] = bias;
      }
      #pragma unroll
      for (int kt = 0; kt < 8; ++kt){
        bf16x8 a[2], b[4];
        #pragma unroll
        for (int mt = 0; mt < 2; ++mt)
          a[mt] = *(const bf16x8*)&lds_w1[abase[mt] + (((kt*4 + q) ^ akey[mt]) << 3)];
        #pragma unroll
        for (int nt = 0; nt < 4; ++nt)
          b[nt] = *(const bf16x8*)&lds_sb[bbase[nt] + (((kt*4 + q) ^ bkey[nt]) << 3)];
        #pragma unroll
        for (int mt = 0; mt < 2; ++mt)
          #pragma unroll
          for (int nt = 0; nt < 4; ++nt)
            g[mt][nt] = __builtin_amdgcn_mfma_f32_16x16x32_bf16(a[mt], b[nt], g[mt][nt], 0, 0, 0);
      }
      __syncthreads();

      // z = tanh(.) -> SB
      #pragma unroll
      for (int mt = 0; mt < 2; ++mt)
        #pragma unroll
        for (int nt = 0; nt < 4; ++nt){
          float v0 = fast_tanh(g[mt][nt][0]);
          float v1 = fast_tanh(g[mt][nt][1]);
          float v2 = fast_tanh(g[mt][nt][2]);
          float v3 = fast_tanh(g[mt][nt][3]);
          uint32x2 wv = { cvt_pk_bf16(v0, v1), cvt_pk_bf16(v2, v3) };
          *(uint32x2*)&lds_sb[woff[mt][nt]] = wv;
        }
      __syncthreads();

      // GEMM2: k^T = W2^T @ z^T (+b2), A streamed from L2-resident W2T
      #pragma unroll
      for (int mt = 0; mt < 2; ++mt)
        #pragma unroll
        for (int nt = 0; nt < 4; ++nt)
          g[mt][nt] = b2v[mt];
      bf16x8 a_c[2], a_n[2];
      #pragma unroll
      for (int mt = 0; mt < 2; ++mt)
        a_c[mt] = *(const bf16x8*)&W2Tg[arow[mt]*256 + q*8];
      #pragma unroll
      for (int kt = 0; kt < 8; ++kt){
        if (kt < 7){
          #pragma unroll
          for (int mt = 0; mt < 2; ++mt)
            a_n[mt] = *(const bf16x8*)&W2Tg[arow[mt]*256 + (kt+1)*32 + q*8];
        }
        bf16x8 b[4];
        #pragma unroll
        for (int nt = 0; nt < 4; ++nt)
          b[nt] = *(const bf16x8*)&lds_sb[bbase[nt] + (((kt*4 + q) ^ bkey[nt]) << 3)];
        #pragma unroll
        for (int mt = 0; mt < 2; ++mt)
          #pragma unroll
          for (int nt = 0; nt < 4; ++nt)
            g[mt][nt] = __builtin_amdgcn_mfma_f32_16x16x32_bf16(a_c[mt], b[nt], g[mt][nt], 0, 0, 0);
        if (kt < 7){
          #pragma unroll
          for (int mt = 0; mt < 2; ++mt) a_c[mt] = a_n[mt];
        }
      }

      // RK4 sum
      #pragma unroll
      for (int mt = 0; mt < 2; ++mt)
        #pragma unroll
        for (int nt = 0; nt < 4; ++nt)
          #pragma unroll
          for (int r = 0; r < 4; ++r)
            sm[mt][nt][r] = __builtin_fmaf(we, g[mt][nt][r], sm[mt][nt][r]);
    } // evals

    #pragma unroll
    for (int mt = 0; mt < 2; ++mt)
      #pragma unroll
      for (int nt = 0; nt < 4; ++nt)
        #pragma unroll
        for (int r = 0; r < 4; ++r)
          hv[mt][nt][r] = __builtin_fmaf(dt6, sm[mt][nt][r], hv[mt][nt][r]);
  } // steps

  // ---- epilogue: h_T -> SB, then out = h_T @ Wout + bout (VALU, tiny) ----
  __syncthreads();
  #pragma unroll
  for (int mt = 0; mt < 2; ++mt)
    #pragma unroll
    for (int nt = 0; nt < 4; ++nt){
      uint32x2 wv = { cvt_pk_bf16(hv[mt][nt][0], hv[mt][nt][1]),
                      cvt_pk_bf16(hv[mt][nt][2], hv[mt][nt][3]) };
      *(uint32x2*)&lds_sb[woff[mt][nt]] = wv;
    }
  __syncthreads();
  {
    const int ml = tid & 63;
    const int og = tid >> 6;           // 8 wave-groups; first 6 cover 18 outputs
    if (og < 6){
      const int obase = og * 3;
      float acc[3] = {0.f, 0.f, 0.f};
      for (int c = 0; c < 32; ++c){
        bf16x8 h8 = *(const bf16x8*)&lds_sb[ml*256 + ((c ^ (ml & 31)) << 3)];
        #pragma unroll
        for (int j = 0; j < 8; ++j){
          float hval = bf2f(h8[j]);
          int kk = c*8 + j;
          #pragma unroll
          for (int oo = 0; oo < 3; ++oo)
            acc[oo] += hval * Wout[kk*18 + obase + oo];
        }
      }
      #pragma unroll
      for (int oo = 0; oo < 3; ++oo)
        out[(size_t)(m0 + ml)*18 + obase + oo] = acc[oo] + bout[obase + oo];
    }
  }
}

extern "C" void kernel_launch(void* const* d_in, const int* in_sizes, int n_in,
                              void* d_out, int out_size, void* d_ws, size_t ws_size,
                              hipStream_t stream){
  const float* x   = (const float*)d_in[0];
  const float* Ws  = (const float*)d_in[1];
  const float* bs  = (const float*)d_in[2];
  const float* W1  = (const float*)d_in[3];
  const float* b1  = (const float*)d_in[4];
  const float* W2  = (const float*)d_in[5];
  const float* b2  = (const float*)d_in[6];
  const float* Wo  = (const float*)d_in[7];
  const float* bo  = (const float*)d_in[8];
  float* out = (float*)d_out;

  __bf16* WsT = (__bf16*)d_ws;          // 256x512 bf16 = 256 KB
  __bf16* W1T = WsT + 512*256;          // 256x256 bf16 = 128 KB
  __bf16* W2T = W1T + 256*256;          // 256x256 bf16 = 128 KB

  prep_kernel<<<128, 256, 0, stream>>>(Ws, W1, W2, WsT, W1T, W2T);
  ode_kernel<<<256, 512, 0, stream>>>(x, bs, W1, b1, b2, Wo, bo, WsT, W1T, W2T, out);
}

// Round 3
// 861.065 us; speedup vs baseline: 1.3673x; 1.3231x over previous
//
#include <hip/hip_runtime.h>
#include <stdint.h>

#define NSTEPS 40

typedef float    floatx4  __attribute__((ext_vector_type(4)));
typedef __bf16   bf16x8   __attribute__((ext_vector_type(8)));
typedef uint32_t uint32x2 __attribute__((ext_vector_type(2)));

__device__ __forceinline__ __bf16 f2bf(float f){
  union { float f; uint32_t u; } v; v.f = f;
  uint32_t r = v.u + 0x7FFFu + ((v.u >> 16) & 1u);   // RNE (prep kernel only)
  union { uint16_t s; __bf16 b; } o; o.s = (uint16_t)(r >> 16);
  return o.b;
}
__device__ __forceinline__ float bf2f(__bf16 b){
  union { uint16_t s; __bf16 b; } i; i.b = b;
  union { uint32_t u; float f; } o; o.u = ((uint32_t)i.s) << 16;
  return o.f;
}
// HW packed f32x2 -> bf16x2 (RNE), 1 instruction
__device__ __forceinline__ uint32_t cvt_pk_bf16(float lo, float hi){
  uint32_t d;
  asm("v_cvt_pk_bf16_f32 %0, %1, %2" : "=v"(d) : "v"(lo), "v"(hi));
  return d;
}
__device__ __forceinline__ float fast_tanh(float x){
  float e = __expf(2.0f * x);
  return __builtin_fmaf(-2.0f, __builtin_amdgcn_rcpf(e + 1.0f), 1.0f);
}

// ---- prep: bf16-cast + transpose weights into workspace ----
__global__ void prep_kernel(const float* __restrict__ Ws,
                            const float* __restrict__ W1,
                            const float* __restrict__ W2,
                            __bf16* __restrict__ WsT,
                            __bf16* __restrict__ W1T,
                            __bf16* __restrict__ W2T){
  int tid = blockIdx.x * blockDim.x + threadIdx.x;
  int stride = gridDim.x * blockDim.x;
  for (int i = tid; i < 512*256; i += stride){
    int k = i >> 8, n = i & 255;
    WsT[n*512 + k] = f2bf(Ws[i]);
  }
  for (int i = tid; i < 256*256; i += stride){
    int k = i >> 8, n = i & 255;
    W1T[n*256 + k] = f2bf(W1[i]);
    W2T[n*256 + k] = f2bf(W2[i]);
  }
}

// Fused ODE kernel. Block = 64 batch rows, 512 threads (8 waves, 2/SIMD).
// Wave w owns hid rows [32w, 32w+32). W1^T and W2^T A-fragments are held
// PERMANENTLY in registers (64 VGPRs each) — zero per-eval weight traffic.
// LDS: double-buffered state (SB0 = h_eval, SB1 = z), 32 KB each, + 3 KB
// bias table -> 2 barriers per eval instead of 4.
// SB swizzle: 16B chunk c of row m lives at chunk (c ^ (m&31)).
__global__ __launch_bounds__(512, 2)
void ode_kernel(const float* __restrict__ x,
                const float* __restrict__ b_state,
                const float* __restrict__ W1full,   // 257x256 fp32 (row 256 = t row)
                const float* __restrict__ b1,
                const float* __restrict__ b2,
                const float* __restrict__ Wout,     // 256x18 fp32
                const float* __restrict__ bout,
                const __bf16* __restrict__ WsT,     // [256][512]
                const __bf16* __restrict__ W1Tg,    // [256][256]
                const __bf16* __restrict__ W2Tg,    // [256][256]
                float* __restrict__ out)
{
  __shared__ __align__(16) __bf16 lds_sb0[64*256];  // 32 KB  h_eval
  __shared__ __align__(16) __bf16 lds_sb1[64*256];  // 32 KB  z
  __shared__ __align__(16) float  lds_bias[3*256];  //  3 KB  b1 | w_t | b2

  const int tid  = threadIdx.x;
  const int wave = tid >> 6;       // 0..7
  const int lane = tid & 63;
  const int c16  = lane & 15;
  const int q    = lane >> 4;      // 0..3
  const int nh0  = wave * 32;      // this wave's hid-row base
  const int m0   = blockIdx.x * 64;

  // ---- stage bias table ----
  if (tid < 256){
    lds_bias[tid]       = b1[tid];
    lds_bias[256 + tid] = W1full[256*256 + tid];  // time row of W_dyn1
    lds_bias[512 + tid] = b2[tid];
  }

  // ---- per-lane addressing ----
  int arow[2];
  #pragma unroll
  for (int mt = 0; mt < 2; ++mt) arow[mt] = nh0 + mt*16 + c16;
  int bbase[4], bkey[4];
  #pragma unroll
  for (int nt = 0; nt < 4; ++nt){
    int m = nt*16 + c16;
    bbase[nt] = m*256; bkey[nt] = m & 31;
  }
  int woff[2][4];
  #pragma unroll
  for (int mt = 0; mt < 2; ++mt){
    int n0 = nh0 + mt*16 + 4*q;
    #pragma unroll
    for (int nt = 0; nt < 4; ++nt)
      woff[mt][nt] = bbase[nt] + (((n0 >> 3) ^ bkey[nt]) << 3) + (n0 & 7);
  }
  const int bidx = nh0 + 4*q;       // bias row base (add mt*16)

  // ---- resident weight fragments: W1^T, W2^T (A-operands) ----
  bf16x8 w1f[2][8], w2f[2][8];
  #pragma unroll
  for (int mt = 0; mt < 2; ++mt)
    #pragma unroll
    for (int kt = 0; kt < 8; ++kt){
      w1f[mt][kt] = *(const bf16x8*)&W1Tg[arow[mt]*256 + kt*32 + q*8];
      w2f[mt][kt] = *(const bf16x8*)&W2Tg[arow[mt]*256 + kt*32 + q*8];
    }

  floatx4 g[2][4], hv[2][4];       // [hid-tile mt][batch-tile nt]

  // ---- phase 0: h0^T = tanh(Ws^T @ x^T + b_state) ----
  {
    #pragma unroll
    for (int mt = 0; mt < 2; ++mt){
      floatx4 bsv;
      #pragma unroll
      for (int r = 0; r < 4; ++r) bsv[r] = b_state[nh0 + mt*16 + 4*q + r];
      #pragma unroll
      for (int nt = 0; nt < 4; ++nt) g[mt][nt] = bsv;
    }
    #pragma unroll 4
    for (int kt = 0; kt < 16; ++kt){
      bf16x8 a[2], b[4];
      #pragma unroll
      for (int mt = 0; mt < 2; ++mt)
        a[mt] = *(const bf16x8*)&WsT[arow[mt]*512 + kt*32 + q*8];
      #pragma unroll
      for (int nt = 0; nt < 4; ++nt){
        const float* px = &x[(size_t)(m0 + nt*16 + c16)*512 + kt*32 + q*8];
        floatx4 f0 = *(const floatx4*)px;
        floatx4 f1 = *(const floatx4*)(px + 4);
        union { uint32_t u[4]; bf16x8 v; } pk;
        pk.u[0] = cvt_pk_bf16(f0[0], f0[1]);
        pk.u[1] = cvt_pk_bf16(f0[2], f0[3]);
        pk.u[2] = cvt_pk_bf16(f1[0], f1[1]);
        pk.u[3] = cvt_pk_bf16(f1[2], f1[3]);
        b[nt] = pk.v;
      }
      #pragma unroll
      for (int mt = 0; mt < 2; ++mt)
        #pragma unroll
        for (int nt = 0; nt < 4; ++nt)
          g[mt][nt] = __builtin_amdgcn_mfma_f32_16x16x32_bf16(a[mt], b[nt], g[mt][nt], 0, 0, 0);
    }
    #pragma unroll
    for (int mt = 0; mt < 2; ++mt)
      #pragma unroll
      for (int nt = 0; nt < 4; ++nt)
        #pragma unroll
        for (int r = 0; r < 4; ++r)
          hv[mt][nt][r] = fast_tanh(g[mt][nt][r]);
  }

  const float dt  = 1.0f / NSTEPS;
  const float dt6 = dt / 6.0f;
  const floatx4 vzero = {0.f, 0.f, 0.f, 0.f};

  #pragma unroll 1
  for (int s = 0; s < NSTEPS; ++s){
    float tbase = dt * (float)s;
    floatx4 sm[2][4];
    #pragma unroll
    for (int mt = 0; mt < 2; ++mt)
      #pragma unroll
      for (int nt = 0; nt < 4; ++nt)
        sm[mt][nt] = vzero;

    #pragma unroll 1
    for (int e = 0; e < 4; ++e){
      float half_or_full = (e == 3) ? dt : 0.5f * dt;
      float cin = (e == 0) ? 0.0f : half_or_full;   // h_eval = h + cin*k_prev
      float te  = tbase + ((e == 0) ? 0.0f : half_or_full);
      float we  = (e == 1 || e == 2) ? 2.0f : 1.0f;

      // write h_eval -> SB0 (g = k_{e-1}; cin=0 at e=0).
      // SB0's last readers (GEMM1 of prev eval) passed barrier B since.
      #pragma unroll
      for (int mt = 0; mt < 2; ++mt)
        #pragma unroll
        for (int nt = 0; nt < 4; ++nt){
          float v0 = __builtin_fmaf(cin, g[mt][nt][0], hv[mt][nt][0]);
          float v1 = __builtin_fmaf(cin, g[mt][nt][1], hv[mt][nt][1]);
          float v2 = __builtin_fmaf(cin, g[mt][nt][2], hv[mt][nt][2]);
          float v3 = __builtin_fmaf(cin, g[mt][nt][3], hv[mt][nt][3]);
          uint32x2 wv = { cvt_pk_bf16(v0, v1), cvt_pk_bf16(v2, v3) };
          *(uint32x2*)&lds_sb0[woff[mt][nt]] = wv;
        }
      __syncthreads();   // barrier A

      // GEMM1: z^T = W1^T @ h_eval^T (+ b1 + t*w_t); A resident in regs
      #pragma unroll
      for (int mt = 0; mt < 2; ++mt){
        floatx4 b1v = *(const floatx4*)&lds_bias[bidx + mt*16];
        floatx4 wtv = *(const floatx4*)&lds_bias[256 + bidx + mt*16];
        floatx4 bias;
        #pragma unroll
        for (int r = 0; r < 4; ++r) bias[r] = __builtin_fmaf(te, wtv[r], b1v[r]);
        #pragma unroll
        for (int nt = 0; nt < 4; ++nt) g[mt][nt] = bias;
      }
      #pragma unroll
      for (int kt = 0; kt < 8; ++kt){
        bf16x8 b[4];
        #pragma unroll
        for (int nt = 0; nt < 4; ++nt)
          b[nt] = *(const bf16x8*)&lds_sb0[bbase[nt] + (((kt*4 + q) ^ bkey[nt]) << 3)];
        #pragma unroll
        for (int mt = 0; mt < 2; ++mt)
          #pragma unroll
          for (int nt = 0; nt < 4; ++nt)
            g[mt][nt] = __builtin_amdgcn_mfma_f32_16x16x32_bf16(w1f[mt][kt], b[nt], g[mt][nt], 0, 0, 0);
      }

      // z = tanh(.) -> SB1. Safe: SB1's last readers (GEMM2 of prev eval)
      // passed barrier A since.
      #pragma unroll
      for (int mt = 0; mt < 2; ++mt)
        #pragma unroll
        for (int nt = 0; nt < 4; ++nt){
          float v0 = fast_tanh(g[mt][nt][0]);
          float v1 = fast_tanh(g[mt][nt][1]);
          float v2 = fast_tanh(g[mt][nt][2]);
          float v3 = fast_tanh(g[mt][nt][3]);
          uint32x2 wv = { cvt_pk_bf16(v0, v1), cvt_pk_bf16(v2, v3) };
          *(uint32x2*)&lds_sb1[woff[mt][nt]] = wv;
        }
      __syncthreads();   // barrier B

      // GEMM2: k^T = W2^T @ z^T (+b2); A resident in regs
      #pragma unroll
      for (int mt = 0; mt < 2; ++mt){
        floatx4 b2v = *(const floatx4*)&lds_bias[512 + bidx + mt*16];
        #pragma unroll
        for (int nt = 0; nt < 4; ++nt) g[mt][nt] = b2v;
      }
      #pragma unroll
      for (int kt = 0; kt < 8; ++kt){
        bf16x8 b[4];
        #pragma unroll
        for (int nt = 0; nt < 4; ++nt)
          b[nt] = *(const bf16x8*)&lds_sb1[bbase[nt] + (((kt*4 + q) ^ bkey[nt]) << 3)];
        #pragma unroll
        for (int mt = 0; mt < 2; ++mt)
          #pragma unroll
          for (int nt = 0; nt < 4; ++nt)
            g[mt][nt] = __builtin_amdgcn_mfma_f32_16x16x32_bf16(w2f[mt][kt], b[nt], g[mt][nt], 0, 0, 0);
      }

      // RK4 sum
      #pragma unroll
      for (int mt = 0; mt < 2; ++mt)
        #pragma unroll
        for (int nt = 0; nt < 4; ++nt)
          #pragma unroll
          for (int r = 0; r < 4; ++r)
            sm[mt][nt][r] = __builtin_fmaf(we, g[mt][nt][r], sm[mt][nt][r]);
    } // evals

    #pragma unroll
    for (int mt = 0; mt < 2; ++mt)
      #pragma unroll
      for (int nt = 0; nt < 4; ++nt)
        #pragma unroll
        for (int r = 0; r < 4; ++r)
          hv[mt][nt][r] = __builtin_fmaf(dt6, sm[mt][nt][r], hv[mt][nt][r]);
  } // steps

  // ---- epilogue: h_T -> SB0, then out = h_T @ Wout + bout ----
  // SB0 safe to overwrite (last readers passed barrier B of final eval).
  #pragma unroll
  for (int mt = 0; mt < 2; ++mt)
    #pragma unroll
    for (int nt = 0; nt < 4; ++nt){
      uint32x2 wv = { cvt_pk_bf16(hv[mt][nt][0], hv[mt][nt][1]),
                      cvt_pk_bf16(hv[mt][nt][2], hv[mt][nt][3]) };
      *(uint32x2*)&lds_sb0[woff[mt][nt]] = wv;
    }
  __syncthreads();
  {
    const int ml = tid & 63;
    const int og = tid >> 6;           // 8 wave-groups; first 6 cover 18 outputs
    if (og < 6){
      const int obase = og * 3;
      float acc[3] = {0.f, 0.f, 0.f};
      for (int c = 0; c < 32; ++c){
        bf16x8 h8 = *(const bf16x8*)&lds_sb0[ml*256 + ((c ^ (ml & 31)) << 3)];
        #pragma unroll
        for (int j = 0; j < 8; ++j){
          float hval = bf2f(h8[j]);
          int kk = c*8 + j;
          #pragma unroll
          for (int oo = 0; oo < 3; ++oo)
            acc[oo] += hval * Wout[kk*18 + obase + oo];
        }
      }
      #pragma unroll
      for (int oo = 0; oo < 3; ++oo)
        out[(size_t)(m0 + ml)*18 + obase + oo] = acc[oo] + bout[obase + oo];
    }
  }
}

extern "C" void kernel_launch(void* const* d_in, const int* in_sizes, int n_in,
                              void* d_out, int out_size, void* d_ws, size_t ws_size,
                              hipStream_t stream){
  const float* x   = (const float*)d_in[0];
  const float* Ws  = (const float*)d_in[1];
  const float* bs  = (const float*)d_in[2];
  const float* W1  = (const float*)d_in[3];
  const float* b1  = (const float*)d_in[4];
  const float* W2  = (const float*)d_in[5];
  const float* b2  = (const float*)d_in[6];
  const float* Wo  = (const float*)d_in[7];
  const float* bo  = (const float*)d_in[8];
  float* out = (float*)d_out;

  __bf16* WsT = (__bf16*)d_ws;          // 256x512 bf16 = 256 KB
  __bf16* W1T = WsT + 512*256;          // 256x256 bf16 = 128 KB
  __bf16* W2T = W1T + 256*256;          // 256x256 bf16 = 128 KB

  prep_kernel<<<128, 256, 0, stream>>>(Ws, W1, W2, WsT, W1T, W2T);
  ode_kernel<<<256, 512, 0, stream>>>(x, bs, W1, b1, b2, Wo, bo, WsT, W1T, W2T, out);
}